// Round 17
// baseline (136.117 us; speedup 1.0000x reference)
//
#include <hip/hip_runtime.h>

// ---------------------------------------------------------------------------
// LIIF forward, bf16-MFMA, round 17.
//   Round 16 base + 2-row conv blocks for c3/c4/l0:
//   block = 2 image rows x 32 Cout x K-split(2); 8 waves = 2 kg x {2 rows x
//   2 n-halves}; grid stays 512, 2 blocks/CU. Per-block weight reads halve
//   (294->147 KB) => total weight L2 traffic 150->75 MB/conv. Halo staging
//   2 rows/output-row instead of 3. Inner loop/swizzle/prefetch unchanged.
// ---------------------------------------------------------------------------

#define HW    4096
#define Bc    2
#define Qn    8192
#define BQ    16384   // Bc*Qn
#define NPX   8192    // Bc*HW

typedef __attribute__((ext_vector_type(8))) short short8;
typedef __attribute__((ext_vector_type(4))) float f32x4;

__device__ __forceinline__ unsigned short f2bf(float f) {
    unsigned int u = __builtin_bit_cast(unsigned int, f);
    u += 0x7FFFu + ((u >> 16) & 1u);            // RNE
    return (unsigned short)(u >> 16);
}
__device__ __forceinline__ float bflo(unsigned int u) {
    return __builtin_bit_cast(float, u << 16);
}
__device__ __forceinline__ float bfhi(unsigned int u) {
    return __builtin_bit_cast(float, u & 0xffff0000u);
}
__device__ __forceinline__ unsigned int pack2(float a, float b) {
    return (unsigned int)f2bf(a) | ((unsigned int)f2bf(b) << 16);
}

// ---------------- merged: c1 conv (blocks 0..255) + weight prep ------------
#define CO_T  16
#define ROWS  2

__global__ __launch_bounds__(256) void prep_c1_kernel(
    const float* __restrict__ in,  const float* __restrict__ c1w,
    const float* __restrict__ c1b,
    const float* __restrict__ c2w, const float* __restrict__ c3w,
    const float* __restrict__ c4w, const float* __restrict__ w0,
    const float* __restrict__ w1,  const float* __restrict__ w2,
    const float* __restrict__ w3,
    short* __restrict__ t1,
    short* __restrict__ wc2, short* __restrict__ wc3,
    short* __restrict__ wc4, short* __restrict__ wl0,
    short* __restrict__ wt1, short* __restrict__ wt2,
    short* __restrict__ wt3)
{
    __shared__ float sin_[3][ROWS + 2][66];
    __shared__ float sw_[CO_T][3][9];

    int tid = threadIdx.x;

    if (blockIdx.x < 256) {
        const int Cin = 3, Cout = 64;
        int bx = blockIdx.x;
        int rowb = bx & 31; bx >>= 5;
        int cob = bx & 3;
        int b   = bx >> 2;

        int x  = tid & 63;
        int wq = tid >> 6;
        int y0 = rowb * ROWS;

        float acc[4][ROWS];
#pragma unroll
        for (int k = 0; k < 4; ++k)
#pragma unroll
            for (int r = 0; r < ROWS; ++r) acc[k][r] = 0.f;

        int tot_in = 3 * (ROWS + 2) * 66;
        for (int idx = tid; idx < tot_in; idx += 256) {
            int xx = idx % 66;
            int t2 = idx / 66;
            int rr = t2 % (ROWS + 2);
            int c  = t2 / (ROWS + 2);
            int gy = y0 - 1 + rr;
            int gx = xx - 1;
            float v = 0.f;
            if (gy >= 0 && gy < 64 && gx >= 0 && gx < 64)
                v = in[((size_t)b * Cin + c) * HW + gy * 64 + gx];
            sin_[c][rr][xx] = v;
        }
        int tot_w = CO_T * 3 * 9;
        for (int idx = tid; idx < tot_w; idx += 256) {
            int t  = idx % 9;
            int t2 = idx / 9;
            int c  = t2 % 3;
            int col = t2 / 3;
            sw_[col][c][t] = c1w[((size_t)(cob * CO_T + col) * Cin + c) * 9 + t];
        }
        __syncthreads();

#pragma unroll
        for (int c = 0; c < 3; ++c) {
            float iv[ROWS + 2][3];
#pragma unroll
            for (int rr = 0; rr < ROWS + 2; ++rr)
#pragma unroll
                for (int d = 0; d < 3; ++d)
                    iv[rr][d] = sin_[c][rr][x + d];
#pragma unroll
            for (int k = 0; k < 4; ++k) {
                float wv[9];
#pragma unroll
                for (int t = 0; t < 9; ++t) wv[t] = sw_[wq * 4 + k][c][t];
#pragma unroll
                for (int kh = 0; kh < 3; ++kh)
#pragma unroll
                    for (int kw = 0; kw < 3; ++kw) {
                        float wvv = wv[kh * 3 + kw];
#pragma unroll
                        for (int r = 0; r < ROWS; ++r)
                            acc[k][r] = fmaf(iv[r + kh][kw], wvv, acc[k][r]);
                    }
            }
        }

#pragma unroll
        for (int k = 0; k < 4; ++k) {
            int co = cob * CO_T + wq * 4 + k;
            float bv = c1b[co];
#pragma unroll
            for (int r = 0; r < ROWS; ++r) {
                float v = fmaxf(acc[k][r] + bv, 0.f);
                int pos = (y0 + r) * 64 + x;
                t1[((size_t)b * HW + pos) * Cout + co] = (short)f2bf(v);
            }
        }
        return;
    }

    const int S1 = 9 * 128 * 64;
    const int S2 = 9 * 256 * 128;
    const int S3 = 9 * 256 * 256;
    int i = (blockIdx.x - 256) * 256 + tid;
    if (i < S1) {
        int ci = i & 63, co = (i >> 6) & 127, t = i >> 13;
        wc2[i] = (short)f2bf(c2w[((size_t)co * 64 + ci) * 9 + t]);
        return;
    }
    i -= S1;
    if (i < S2) {
        int ci = i & 127, co = (i >> 7) & 255, t = i >> 15;
        wc3[i] = (short)f2bf(c3w[((size_t)co * 128 + ci) * 9 + t]);
        return;
    }
    i -= S2;
    if (i < S3) {
        int ci = i & 255, co = (i >> 8) & 255, t = i >> 16;
        wc4[i] = (short)f2bf(c4w[((size_t)co * 256 + ci) * 9 + t]);
        return;
    }
    i -= S3;
    if (i < S3) {
        int ci = i & 255, co = (i >> 8) & 255, t = i >> 16;
        wl0[i] = (short)f2bf(w0[((size_t)ci * 9 + t) * 256 + co]);
        return;
    }
    i -= S3;
    if (i < 65536) { wt1[i] = (short)f2bf(w1[(size_t)(i & 255) * 256 + (i >> 8)]); return; }
    i -= 65536;
    if (i < 65536) { wt2[i] = (short)f2bf(w2[(size_t)(i & 255) * 256 + (i >> 8)]); return; }
    i -= 65536;
    if (i < 65536) { wt3[i] = (short)f2bf(w3[(size_t)(i & 255) * 256 + (i >> 8)]); }
}

// ---------------- K-split conv (c2): 512 thr = 2 k-groups x 4 waves --------
template<int CINF, int CHUNK>
__global__ __launch_bounds__(512) void conv512_kernel(
    const short* __restrict__ in, const short* __restrict__ wt9,
    const float* __restrict__ bias, short* __restrict__ out,
    int Cout, int do_relu)
{
    constexpr int KHALF  = CINF / 2;
    constexpr int NGc    = CHUNK / 8;
    constexpr int SWM    = NGc - 1;
    constexpr int NSTEPg = KHALF / 32;
    __shared__ short s_in[2][3 * 66 * CHUNK];

    int bx  = blockIdx.x;
    int y   = bx & 63; bx >>= 6;
    int nco = Cout >> 6;
    int cob = bx % nco;
    int b   = bx / nco;

    int tid  = threadIdx.x;
    int kg   = tid >> 8;
    int ltid = tid & 255;
    int wv   = (tid >> 6) & 3;
    int lane = tid & 63;
    int l15  = lane & 15, lk = lane >> 4;
    int n_wave = cob * 64 + wv * 16;
    int koff = kg * KHALF;

    const short* wbase = &wt9[((size_t)(n_wave + l15)) * CINF + koff + lk * 8];
    const size_t tstride = (size_t)Cout * CINF;

    f32x4 acc[4];
#pragma unroll
    for (int mf = 0; mf < 4; ++mf) acc[mf] = (f32x4){0.f, 0.f, 0.f, 0.f};

    short8 bbA[9], bbB[9];
#pragma unroll
    for (int t = 0; t < 9; ++t)
        bbA[t] = *(const short8*)&wbase[t * tstride];

#pragma unroll
    for (int step = 0; step < NSTEPg; ++step) {
        const int kabs = step * 32;
        const int chnk = kabs / CHUNK;
        const int kk   = kabs % CHUNK;
        if (kk == 0) {
            if (step) __syncthreads();
            const int ci0 = koff + chnk * CHUNK;
            for (int i = ltid; i < 3 * 66 * NGc; i += 256) {
                int g   = i % NGc;
                int pos = i / NGc;
                int xx  = pos % 66, rr = pos / 66;
                int gy = y + rr - 1, gx = xx - 1;
                uint4 v = {0u, 0u, 0u, 0u};
                if (gy >= 0 && gy < 64 && gx >= 0 && gx < 64)
                    v = *(const uint4*)&in[((size_t)((b * 64 + gy) * 64 + gx)) * CINF
                                           + ci0 + g * 8];
                *(uint4*)&s_in[kg][pos * CHUNK + ((g ^ (xx & SWM)) * 8)] = v;
            }
            __syncthreads();
        }
        if (step + 1 < NSTEPg) {
            const int nk = (step + 1) * 32;
            if (step & 1) {
#pragma unroll
                for (int t = 0; t < 9; ++t)
                    bbA[t] = *(const short8*)&wbase[t * tstride + nk];
            } else {
#pragma unroll
                for (int t = 0; t < 9; ++t)
                    bbB[t] = *(const short8*)&wbase[t * tstride + nk];
            }
        }
        const int gbase = kk >> 3;
#pragma unroll
        for (int t = 0; t < 9; ++t) {
            const int kh = t / 3, kw = t % 3;
            short8 a[4];
#pragma unroll
            for (int mf = 0; mf < 4; ++mf) {
                int xx = mf * 16 + l15 + kw;
                int g  = (gbase + lk) ^ (xx & SWM);
                a[mf] = *(const short8*)&s_in[kg][(kh * 66 + xx) * CHUNK + g * 8];
            }
            short8 cur = (step & 1) ? bbB[t] : bbA[t];
#pragma unroll
            for (int mf = 0; mf < 4; ++mf)
                acc[mf] = __builtin_amdgcn_mfma_f32_16x16x32_bf16(
                    cur, a[mf], acc[mf], 0, 0, 0);   // swapped: D[n][m]
        }
    }

    __syncthreads();
    float* epi = (float*)&s_in[0][0];
    if (kg == 1) {
        float* dst = &epi[((wv * 64 + lane) * 4) * 4];
#pragma unroll
        for (int mf = 0; mf < 4; ++mf)
            *(f32x4*)&dst[mf * 4] = acc[mf];
    }
    __syncthreads();
    if (kg == 0) {
        const float* src = &epi[((wv * 64 + lane) * 4) * 4];
        int n = n_wave + lk * 4;
        float4 bv = *(const float4*)&bias[n];
#pragma unroll
        for (int mf = 0; mf < 4; ++mf) {
            f32x4 o = *(const f32x4*)&src[mf * 4];
            int x = mf * 16 + l15;
            float v0 = acc[mf][0] + o[0] + bv.x;
            float v1 = acc[mf][1] + o[1] + bv.y;
            float v2 = acc[mf][2] + o[2] + bv.z;
            float v3 = acc[mf][3] + o[3] + bv.w;
            if (do_relu) {
                v0 = fmaxf(v0, 0.f); v1 = fmaxf(v1, 0.f);
                v2 = fmaxf(v2, 0.f); v3 = fmaxf(v3, 0.f);
            }
            ushort4 pk;
            pk.x = f2bf(v0); pk.y = f2bf(v1); pk.z = f2bf(v2); pk.w = f2bf(v3);
            *(ushort4*)&out[((size_t)(b * HW + y * 64 + x)) * Cout + n] = pk;
        }
    }
}

// ---------------- 2-row K-split conv (c3/c4/l0): 512 thr -------------------
// block = 2 rows x 32 Cout x K-split(2). 8 waves = kg x {rowsel x nh}.
// Weight reads per block 147 KB (half of r15); staging 4 rows / 2 outputs.
template<int CINF>
__global__ __launch_bounds__(512) void conv2r_kernel(
    const short* __restrict__ in, const short* __restrict__ wt9,
    const float* __restrict__ bias, short* __restrict__ out,
    int Cout, int do_relu)
{
    constexpr int KHALF  = CINF / 2;
    constexpr int CHUNK  = 64;
    constexpr int NGc    = 8;
    constexpr int NSTEPg = KHALF / 32;
    __shared__ short s_in[2][4 * 66 * CHUNK];   // 2 x 33.8 KB

    int bx  = blockIdx.x;
    int rp  = bx & 31; bx >>= 5;                // row-pair 0..31
    int nco = Cout >> 5;                        // 8 for Cout=256
    int cob = bx % nco;
    int b   = bx / nco;
    int y0  = rp * 2;

    int tid  = threadIdx.x;
    int kg   = tid >> 8;                        // k-group 0/1
    int ltid = tid & 255;
    int wv2  = (ltid >> 6) & 3;
    int rowsel = wv2 >> 1;                      // which of the 2 rows
    int nh   = wv2 & 1;                         // n-half
    int lane = tid & 63;
    int l15  = lane & 15, lk = lane >> 4;
    int n_wave = cob * 32 + nh * 16;
    int koff = kg * KHALF;

    const short* wbase = &wt9[((size_t)(n_wave + l15)) * CINF + koff + lk * 8];
    const size_t tstride = (size_t)Cout * CINF;

    f32x4 acc[4];
#pragma unroll
    for (int mf = 0; mf < 4; ++mf) acc[mf] = (f32x4){0.f, 0.f, 0.f, 0.f};

    short8 bbA[9], bbB[9];
#pragma unroll
    for (int t = 0; t < 9; ++t)
        bbA[t] = *(const short8*)&wbase[t * tstride];

#pragma unroll
    for (int step = 0; step < NSTEPg; ++step) {
        const int kabs = step * 32;
        const int chnk = kabs / CHUNK;
        const int kk   = kabs % CHUNK;
        if (kk == 0) {
            if (step) __syncthreads();
            const int ci0 = koff + chnk * CHUNK;
            for (int i = ltid; i < 4 * 66 * NGc; i += 256) {
                int g   = i % NGc;
                int pos = i / NGc;
                int xx  = pos % 66, rr = pos / 66;   // rr 0..3
                int gy = y0 + rr - 1, gx = xx - 1;
                uint4 v = {0u, 0u, 0u, 0u};
                if (gy >= 0 && gy < 64 && gx >= 0 && gx < 64)
                    v = *(const uint4*)&in[((size_t)((b * 64 + gy) * 64 + gx)) * CINF
                                           + ci0 + g * 8];
                *(uint4*)&s_in[kg][pos * CHUNK + ((g ^ (xx & 7)) * 8)] = v;
            }
            __syncthreads();
        }
        if (step + 1 < NSTEPg) {
            const int nk = (step + 1) * 32;
            if (step & 1) {
#pragma unroll
                for (int t = 0; t < 9; ++t)
                    bbA[t] = *(const short8*)&wbase[t * tstride + nk];
            } else {
#pragma unroll
                for (int t = 0; t < 9; ++t)
                    bbB[t] = *(const short8*)&wbase[t * tstride + nk];
            }
        }
        const int gbase = kk >> 3;
#pragma unroll
        for (int t = 0; t < 9; ++t) {
            const int kh = t / 3, kw = t % 3;
            const int rr2 = rowsel + kh;            // 0..3
            short8 a[4];
#pragma unroll
            for (int mf = 0; mf < 4; ++mf) {
                int col = mf * 16 + l15 + kw;       // 0..65
                int g   = (gbase + lk) ^ (col & 7);
                a[mf] = *(const short8*)&s_in[kg][(rr2 * 66 + col) * CHUNK + g * 8];
            }
            short8 cur = (step & 1) ? bbB[t] : bbA[t];
#pragma unroll
            for (int mf = 0; mf < 4; ++mf)
                acc[mf] = __builtin_amdgcn_mfma_f32_16x16x32_bf16(
                    cur, a[mf], acc[mf], 0, 0, 0);   // swapped: D[n][m]
        }
    }

    // combine k-halves via LDS (16 KB, aliases staging)
    __syncthreads();
    float* epi = (float*)&s_in[0][0];
    if (kg == 1) {
        float* dst = &epi[ltid * 16];
#pragma unroll
        for (int mf = 0; mf < 4; ++mf)
            *(f32x4*)&dst[mf * 4] = acc[mf];
    }
    __syncthreads();
    if (kg == 0) {
        const float* src = &epi[ltid * 16];
        int n = n_wave + lk * 4;
        int row = y0 + rowsel;
        float4 bv = *(const float4*)&bias[n];
#pragma unroll
        for (int mf = 0; mf < 4; ++mf) {
            f32x4 o = *(const f32x4*)&src[mf * 4];
            int x = mf * 16 + l15;
            float v0 = acc[mf][0] + o[0] + bv.x;
            float v1 = acc[mf][1] + o[1] + bv.y;
            float v2 = acc[mf][2] + o[2] + bv.z;
            float v3 = acc[mf][3] + o[3] + bv.w;
            if (do_relu) {
                v0 = fmaxf(v0, 0.f); v1 = fmaxf(v1, 0.f);
                v2 = fmaxf(v2, 0.f); v3 = fmaxf(v3, 0.f);
            }
            ushort4 pk;
            pk.x = f2bf(v0); pk.y = f2bf(v1); pk.z = f2bf(v2); pk.w = f2bf(v3);
            *(ushort4*)&out[((size_t)(b * HW + row * 64 + x)) * Cout + n] = pk;
        }
    }
}

// ---------------- per-PIXEL MLP (16 px/block, 1024 thr, K-split) -----------
__device__ __forceinline__ void mlp_ks(
    const short* __restrict__ A, short* __restrict__ Cb,
    float* __restrict__ scratch,
    const short* __restrict__ Wt, const float* __restrict__ bias,
    int kg, int wv, int lane, int l15, int lk, int xw)
{
    int n0 = wv * 32;
    f32x4 acc[2];
#pragma unroll
    for (int nf = 0; nf < 2; ++nf) acc[nf] = (f32x4){0.f, 0.f, 0.f, 0.f};

#pragma unroll
    for (int s = 0; s < 4; ++s) {
        int k0 = kg * 128 + s * 32;
        short8 bb[2];
#pragma unroll
        for (int nf = 0; nf < 2; ++nf)
            bb[nf] = *(const short8*)
                &Wt[(size_t)(n0 + nf * 16 + l15) * 256 + k0 + lk * 8];
        short8 a = *(const short8*)&A[(l15 * 256 + k0 + lk * 8) ^ xw];
#pragma unroll
        for (int nf = 0; nf < 2; ++nf)
            acc[nf] = __builtin_amdgcn_mfma_f32_16x16x32_bf16(
                bb[nf], a, acc[nf], 0, 0, 0);   // swapped: D[n][m=l15]
    }

    int slot = wv * 64 + lane;
    if (kg == 1) {
        *(f32x4*)&scratch[slot * 4]        = acc[0];
        *(f32x4*)&scratch[2048 + slot * 4] = acc[1];
    }
    __syncthreads();
    if (kg == 0) {
        f32x4 o0 = *(const f32x4*)&scratch[slot * 4];
        f32x4 o1 = *(const f32x4*)&scratch[2048 + slot * 4];
#pragma unroll
        for (int nf = 0; nf < 2; ++nf) {
            f32x4 o = nf ? o1 : o0;
            int n = n0 + nf * 16 + lk * 4;
            float4 bv = *(const float4*)&bias[n];
            float v0 = fmaxf(acc[nf][0] + o[0] + bv.x, 0.f);
            float v1 = fmaxf(acc[nf][1] + o[1] + bv.y, 0.f);
            float v2 = fmaxf(acc[nf][2] + o[2] + bv.z, 0.f);
            float v3 = fmaxf(acc[nf][3] + o[3] + bv.w, 0.f);
            ushort4 pk;
            pk.x = f2bf(v0); pk.y = f2bf(v1);
            pk.z = f2bf(v2); pk.w = f2bf(v3);
            *(ushort4*)&Cb[(l15 * 256 + n) ^ xw] = pk;
        }
    }
    __syncthreads();
}

__global__ __launch_bounds__(1024) void pixel_mlp_kernel(
    const short* __restrict__ h0pre,   // [NPX][256] bf16
    const float* __restrict__ cell,
    const float* __restrict__ w0,      // tail rows 2304,2305 (fp32)
    const short* __restrict__ wt1, const short* __restrict__ wt2,
    const short* __restrict__ wt3,
    const float* __restrict__ b1, const float* __restrict__ b2,
    const float* __restrict__ b3,
    const float* __restrict__ w4, const float* __restrict__ b4,
    float* __restrict__ rgb)           // [NPX][3] fp32
{
    __shared__ short bufs[2][16 * 256];   // 16 KB
    __shared__ float scratch[4096];       // 16 KB (tails / combine / sw4)

    int tid  = threadIdx.x;
    int kg   = tid >> 9;                  // 0/1
    int wv   = (tid >> 6) & 7;            // wave within group
    int lane = tid & 63;
    int l15  = lane & 15, lk = lane >> 4;

    float rc0 = cell[0] * 64.f;
    float rc1 = cell[1] * 64.f;

    float* tails = scratch;               // 512 floats
    if (tid < 128)
        ((float4*)tails)[tid] = ((const float4*)&w0[(size_t)2304 * 256])[tid];
    __syncthreads();

    {
        int row = tid >> 6;               // 0..15
        int c   = (tid & 63) * 4;
        int p = blockIdx.x * 16 + row;
        const short* src = &h0pre[(size_t)p * 256];
        int xr = (row & 7) << 3;
        uint2 h4 = *(const uint2*)&src[c];
        float4 t0 = *(const float4*)&tails[c];
        float4 t1v = *(const float4*)&tails[256 + c];
        float v0 = fmaxf(bflo(h4.x) + rc0 * t0.x + rc1 * t1v.x, 0.f);
        float v1 = fmaxf(bfhi(h4.x) + rc0 * t0.y + rc1 * t1v.y, 0.f);
        float v2 = fmaxf(bflo(h4.y) + rc0 * t0.z + rc1 * t1v.z, 0.f);
        float v3 = fmaxf(bfhi(h4.y) + rc0 * t0.w + rc1 * t1v.w, 0.f);
        uint2 pk;
        pk.x = pack2(v0, v1); pk.y = pack2(v2, v3);
        *(uint2*)&bufs[0][(row * 256 + c) ^ xr] = pk;
    }
    __syncthreads();

    int xw = (l15 & 7) << 3;
    mlp_ks(bufs[0], bufs[1], scratch, wt1, b1, kg, wv, lane, l15, lk, xw);
    mlp_ks(bufs[1], bufs[0], scratch, wt2, b2, kg, wv, lane, l15, lk, xw);
    mlp_ks(bufs[0], bufs[1], scratch, wt3, b3, kg, wv, lane, l15, lk, xw);

    float* sw4 = scratch;                 // 768 floats
    if (tid < 192) ((float4*)sw4)[tid] = ((const float4*)w4)[tid];
    __syncthreads();

    {
        int row = tid >> 6;               // 0..15
        int k   = lane * 4;
        const short* hrow = bufs[1];
        int xr = (row & 7) << 3;
        uint2 hv = *(const uint2*)&hrow[(row * 256 + k) ^ xr];
        const float* wp = &sw4[k * 3];
        float a0 = 0.f, a1 = 0.f, a2 = 0.f;
        float f;
        f = bflo(hv.x); a0 = fmaf(f, wp[0], a0); a1 = fmaf(f, wp[1],  a1); a2 = fmaf(f, wp[2],  a2);
        f = bfhi(hv.x); a0 = fmaf(f, wp[3], a0); a1 = fmaf(f, wp[4],  a1); a2 = fmaf(f, wp[5],  a2);
        f = bflo(hv.y); a0 = fmaf(f, wp[6], a0); a1 = fmaf(f, wp[7],  a1); a2 = fmaf(f, wp[8],  a2);
        f = bfhi(hv.y); a0 = fmaf(f, wp[9], a0); a1 = fmaf(f, wp[10], a1); a2 = fmaf(f, wp[11], a2);

#pragma unroll
        for (int m = 1; m < 64; m <<= 1) {
            a0 += __shfl_xor(a0, m);
            a1 += __shfl_xor(a1, m);
            a2 += __shfl_xor(a2, m);
        }
        if (lane == 0) {
            size_t p = (size_t)blockIdx.x * 16 + row;
            rgb[p * 3 + 0] = a0 + b4[0];
            rgb[p * 3 + 1] = a1 + b4[1];
            rgb[p * 3 + 2] = a2 + b4[2];
        }
    }
}

// ---------------- per-query 4-tap weighted gather --------------------------
__global__ __launch_bounds__(256) void query_kernel(
    const float* __restrict__ coord, const float* __restrict__ rgb,
    float* __restrict__ out)
{
    int q = blockIdx.x * 256 + threadIdx.x;
    if (q >= BQ) return;
    int b = q >> 13;

    float c0 = coord[(size_t)q * 2 + 0];
    float c1 = coord[(size_t)q * 2 + 1];
    const float rx = 1.f / 64.f;
    const float lo = -1.f + 1e-6f, hi = 1.f - 1e-6f, eps = 1e-6f;

    float area[4]; int pos[4];
#pragma unroll
    for (int ss = 0; ss < 4; ++ss) {
        float vx = (ss < 2) ? -1.f : 1.f;
        float vy = (ss & 1) ? 1.f : -1.f;
        float cy = fminf(fmaxf(c0 + vx * rx + eps, lo), hi);
        float cx = fminf(fmaxf(c1 + vy * rx + eps, lo), hi);
        int iy = (int)rintf(((cy + 1.f) * 64.f - 1.f) * 0.5f);
        int ix = (int)rintf(((cx + 1.f) * 64.f - 1.f) * 0.5f);
        iy = min(max(iy, 0), 63); ix = min(max(ix, 0), 63);
        float ly = -1.f + iy * (2.f / 63.f);
        float lx = -1.f + ix * (2.f / 63.f);
        float rel0 = (c0 - ly) * 64.f;
        float rel1 = (c1 - lx) * 64.f;
        area[ss] = fabsf(rel0 * rel1) + 1e-9f;
        pos[ss] = iy * 64 + ix;
    }
    float tot = area[0] + area[1] + area[2] + area[3];
    float r0 = 0.f, r1 = 0.f, r2 = 0.f;
#pragma unroll
    for (int ss = 0; ss < 4; ++ss) {
        float wt = area[3 - ss] / tot;
        const float* rp = &rgb[(size_t)((b << 12) + pos[ss]) * 3];
        r0 = fmaf(wt, rp[0], r0);
        r1 = fmaf(wt, rp[1], r1);
        r2 = fmaf(wt, rp[2], r2);
    }
    size_t o = (size_t)q * 3;
    out[o + 0] = r0; out[o + 1] = r1; out[o + 2] = r2;
}

// ---------------------------------------------------------------------------
extern "C" void kernel_launch(void* const* d_in, const int* in_sizes, int n_in,
                              void* d_out, int out_size, void* d_ws, size_t ws_size,
                              hipStream_t stream)
{
    const float* inp   = (const float*)d_in[0];
    const float* coord = (const float*)d_in[1];
    const float* cell  = (const float*)d_in[2];
    const float* c1w = (const float*)d_in[3];  const float* c1b = (const float*)d_in[4];
    const float* c2w = (const float*)d_in[5];  const float* c2b = (const float*)d_in[6];
    const float* c3w = (const float*)d_in[7];  const float* c3b = (const float*)d_in[8];
    const float* c4w = (const float*)d_in[9];  const float* c4b = (const float*)d_in[10];
    const float* w0  = (const float*)d_in[11]; const float* b0  = (const float*)d_in[12];
    const float* w1  = (const float*)d_in[13]; const float* b1  = (const float*)d_in[14];
    const float* w2  = (const float*)d_in[15]; const float* b2  = (const float*)d_in[16];
    const float* w3  = (const float*)d_in[17]; const float* b3  = (const float*)d_in[18];
    const float* w4  = (const float*)d_in[19]; const float* b4  = (const float*)d_in[20];
    float* out = (float*)d_out;

    char* p = (char*)d_ws;
    short* t1  = (short*)p; p += (size_t)4 << 20;        // c1/c3 out
    short* t2  = (short*)p; p += (size_t)4 << 20;        // c2/c4 out
    short* t3  = (short*)p; p += (size_t)4 << 20;        // h0pre
    short* wc2 = (short*)p; p += (size_t)9 * 128 * 64 * 2;
    short* wc3 = (short*)p; p += (size_t)9 * 256 * 128 * 2;
    short* wc4 = (short*)p; p += (size_t)9 * 256 * 256 * 2;
    short* wl0 = (short*)p; p += (size_t)9 * 256 * 256 * 2;
    short* wt1 = (short*)p; p += (size_t)256 * 256 * 2;
    short* wt2 = (short*)p; p += (size_t)256 * 256 * 2;
    short* wt3 = (short*)p; p += (size_t)256 * 256 * 2;
    float* rgb = (float*)p; p += (size_t)NPX * 3 * 4;

    // merged c1 + weight prep
    hipLaunchKernelGGL(prep_c1_kernel, dim3(256 + 6816), dim3(256), 0, stream,
                       inp, c1w, c1b, c2w, c3w, c4w, w0, w1, w2, w3,
                       t1, wc2, wc3, wc4, wl0, wt1, wt2, wt3);

    // encoder: c2 K-split 1-row; c3/c4/l0 2-row 32-Cout K-split (grid 512)
    hipLaunchKernelGGL((conv512_kernel<64, 32>), dim3(Bc * 2 * 64), dim3(512), 0, stream,
                       t1, wc2, c2b, t2, 128, 1);
    hipLaunchKernelGGL((conv2r_kernel<128>), dim3(Bc * 8 * 32), dim3(512), 0, stream,
                       t2, wc3, c3b, t1, 256, 1);
    hipLaunchKernelGGL((conv2r_kernel<256>), dim3(Bc * 8 * 32), dim3(512), 0, stream,
                       t1, wc4, c4b, t2, 256, 1);
    // layer0 as conv: +b0, NO relu -> h0pre
    hipLaunchKernelGGL((conv2r_kernel<256>), dim3(Bc * 8 * 32), dim3(512), 0, stream,
                       t2, wl0, b0, t3, 256, 0);

    // per-pixel MLP (8192 rows, K-split 1024 thr) then 4-tap query gather
    hipLaunchKernelGGL(pixel_mlp_kernel, dim3(NPX / 16), dim3(1024), 0, stream,
                       t3, cell, w0, wt1, wt2, wt3, b1, b2, b3, w4, b4, rgb);
    hipLaunchKernelGGL(query_kernel, dim3(BQ / 256), dim3(256), 0, stream,
                       coord, rgb, out);
}

// Round 18
// 113.138 us; speedup vs baseline: 1.2031x; 1.2031x over previous
//
#include <hip/hip_runtime.h>

// ---------------------------------------------------------------------------
// LIIF forward, bf16-MFMA, round 18 == round 16 verbatim (best measured,
// 113.2us). Round 17's 2-row conv regressed (input-staging traffic x2.7);
// the r15/16 conv config is the measured local optimum:
//   - convs: 1 row x 64-Cout x K-split(2), 512 thr = 2 kg x 4 waves,
//     4Mfrag x 16N, CHUNK=64(32 for c2), 9-tap reg prefetch, XOR swizzle
//   - pixel_mlp: 1024 thr = 2 kg x 8 waves, fp32 LDS combine, shfl final
//   - merged prep+c1; per-query 4-tap gather
// ---------------------------------------------------------------------------

#define HW    4096
#define Bc    2
#define Qn    8192
#define BQ    16384   // Bc*Qn
#define NPX   8192    // Bc*HW

typedef __attribute__((ext_vector_type(8))) short short8;
typedef __attribute__((ext_vector_type(4))) float f32x4;

__device__ __forceinline__ unsigned short f2bf(float f) {
    unsigned int u = __builtin_bit_cast(unsigned int, f);
    u += 0x7FFFu + ((u >> 16) & 1u);            // RNE
    return (unsigned short)(u >> 16);
}
__device__ __forceinline__ float bflo(unsigned int u) {
    return __builtin_bit_cast(float, u << 16);
}
__device__ __forceinline__ float bfhi(unsigned int u) {
    return __builtin_bit_cast(float, u & 0xffff0000u);
}
__device__ __forceinline__ unsigned int pack2(float a, float b) {
    return (unsigned int)f2bf(a) | ((unsigned int)f2bf(b) << 16);
}

// ---------------- merged: c1 conv (blocks 0..255) + weight prep ------------
#define CO_T  16
#define ROWS  2

__global__ __launch_bounds__(256) void prep_c1_kernel(
    const float* __restrict__ in,  const float* __restrict__ c1w,
    const float* __restrict__ c1b,
    const float* __restrict__ c2w, const float* __restrict__ c3w,
    const float* __restrict__ c4w, const float* __restrict__ w0,
    const float* __restrict__ w1,  const float* __restrict__ w2,
    const float* __restrict__ w3,
    short* __restrict__ t1,
    short* __restrict__ wc2, short* __restrict__ wc3,
    short* __restrict__ wc4, short* __restrict__ wl0,
    short* __restrict__ wt1, short* __restrict__ wt2,
    short* __restrict__ wt3)
{
    __shared__ float sin_[3][ROWS + 2][66];
    __shared__ float sw_[CO_T][3][9];

    int tid = threadIdx.x;

    if (blockIdx.x < 256) {
        const int Cin = 3, Cout = 64;
        int bx = blockIdx.x;
        int rowb = bx & 31; bx >>= 5;
        int cob = bx & 3;
        int b   = bx >> 2;

        int x  = tid & 63;
        int wq = tid >> 6;
        int y0 = rowb * ROWS;

        float acc[4][ROWS];
#pragma unroll
        for (int k = 0; k < 4; ++k)
#pragma unroll
            for (int r = 0; r < ROWS; ++r) acc[k][r] = 0.f;

        int tot_in = 3 * (ROWS + 2) * 66;
        for (int idx = tid; idx < tot_in; idx += 256) {
            int xx = idx % 66;
            int t2 = idx / 66;
            int rr = t2 % (ROWS + 2);
            int c  = t2 / (ROWS + 2);
            int gy = y0 - 1 + rr;
            int gx = xx - 1;
            float v = 0.f;
            if (gy >= 0 && gy < 64 && gx >= 0 && gx < 64)
                v = in[((size_t)b * Cin + c) * HW + gy * 64 + gx];
            sin_[c][rr][xx] = v;
        }
        int tot_w = CO_T * 3 * 9;
        for (int idx = tid; idx < tot_w; idx += 256) {
            int t  = idx % 9;
            int t2 = idx / 9;
            int c  = t2 % 3;
            int col = t2 / 3;
            sw_[col][c][t] = c1w[((size_t)(cob * CO_T + col) * Cin + c) * 9 + t];
        }
        __syncthreads();

#pragma unroll
        for (int c = 0; c < 3; ++c) {
            float iv[ROWS + 2][3];
#pragma unroll
            for (int rr = 0; rr < ROWS + 2; ++rr)
#pragma unroll
                for (int d = 0; d < 3; ++d)
                    iv[rr][d] = sin_[c][rr][x + d];
#pragma unroll
            for (int k = 0; k < 4; ++k) {
                float wv[9];
#pragma unroll
                for (int t = 0; t < 9; ++t) wv[t] = sw_[wq * 4 + k][c][t];
#pragma unroll
                for (int kh = 0; kh < 3; ++kh)
#pragma unroll
                    for (int kw = 0; kw < 3; ++kw) {
                        float wvv = wv[kh * 3 + kw];
#pragma unroll
                        for (int r = 0; r < ROWS; ++r)
                            acc[k][r] = fmaf(iv[r + kh][kw], wvv, acc[k][r]);
                    }
            }
        }

#pragma unroll
        for (int k = 0; k < 4; ++k) {
            int co = cob * CO_T + wq * 4 + k;
            float bv = c1b[co];
#pragma unroll
            for (int r = 0; r < ROWS; ++r) {
                float v = fmaxf(acc[k][r] + bv, 0.f);
                int pos = (y0 + r) * 64 + x;
                t1[((size_t)b * HW + pos) * Cout + co] = (short)f2bf(v);
            }
        }
        return;
    }

    const int S1 = 9 * 128 * 64;
    const int S2 = 9 * 256 * 128;
    const int S3 = 9 * 256 * 256;
    int i = (blockIdx.x - 256) * 256 + tid;
    if (i < S1) {
        int ci = i & 63, co = (i >> 6) & 127, t = i >> 13;
        wc2[i] = (short)f2bf(c2w[((size_t)co * 64 + ci) * 9 + t]);
        return;
    }
    i -= S1;
    if (i < S2) {
        int ci = i & 127, co = (i >> 7) & 255, t = i >> 15;
        wc3[i] = (short)f2bf(c3w[((size_t)co * 128 + ci) * 9 + t]);
        return;
    }
    i -= S2;
    if (i < S3) {
        int ci = i & 255, co = (i >> 8) & 255, t = i >> 16;
        wc4[i] = (short)f2bf(c4w[((size_t)co * 256 + ci) * 9 + t]);
        return;
    }
    i -= S3;
    if (i < S3) {
        int ci = i & 255, co = (i >> 8) & 255, t = i >> 16;
        wl0[i] = (short)f2bf(w0[((size_t)ci * 9 + t) * 256 + co]);
        return;
    }
    i -= S3;
    if (i < 65536) { wt1[i] = (short)f2bf(w1[(size_t)(i & 255) * 256 + (i >> 8)]); return; }
    i -= 65536;
    if (i < 65536) { wt2[i] = (short)f2bf(w2[(size_t)(i & 255) * 256 + (i >> 8)]); return; }
    i -= 65536;
    if (i < 65536) { wt3[i] = (short)f2bf(w3[(size_t)(i & 255) * 256 + (i >> 8)]); }
}

// ---------------- K-split conv: 512 thr = 2 k-groups x 4 waves -------------
// Group g computes the same 64x64 tile over K-half g, own LDS buffer.
// Group 1 -> LDS fp32, group 0 combines + bias/relu/store.
template<int CINF, int CHUNK>
__global__ __launch_bounds__(512) void conv512_kernel(
    const short* __restrict__ in, const short* __restrict__ wt9,
    const float* __restrict__ bias, short* __restrict__ out,
    int Cout, int do_relu)
{
    constexpr int KHALF  = CINF / 2;
    constexpr int NGc    = CHUNK / 8;
    constexpr int SWM    = NGc - 1;            // swizzle mask
    constexpr int NSTEPg = KHALF / 32;
    __shared__ short s_in[2][3 * 66 * CHUNK];

    int bx  = blockIdx.x;
    int y   = bx & 63; bx >>= 6;
    int nco = Cout >> 6;
    int cob = bx % nco;
    int b   = bx / nco;

    int tid  = threadIdx.x;
    int kg   = tid >> 8;                       // k-group 0/1
    int ltid = tid & 255;
    int wv   = (tid >> 6) & 3;
    int lane = tid & 63;
    int l15  = lane & 15, lk = lane >> 4;
    int n_wave = cob * 64 + wv * 16;
    int koff = kg * KHALF;

    const short* wbase = &wt9[((size_t)(n_wave + l15)) * CINF + koff + lk * 8];
    const size_t tstride = (size_t)Cout * CINF;

    f32x4 acc[4];
#pragma unroll
    for (int mf = 0; mf < 4; ++mf) acc[mf] = (f32x4){0.f, 0.f, 0.f, 0.f};

    short8 bbA[9], bbB[9];
#pragma unroll
    for (int t = 0; t < 9; ++t)
        bbA[t] = *(const short8*)&wbase[t * tstride];

#pragma unroll
    for (int step = 0; step < NSTEPg; ++step) {
        const int kabs = step * 32;
        const int chnk = kabs / CHUNK;
        const int kk   = kabs % CHUNK;
        if (kk == 0) {
            if (step) __syncthreads();
            const int ci0 = koff + chnk * CHUNK;
            for (int i = ltid; i < 3 * 66 * NGc; i += 256) {
                int g   = i % NGc;
                int pos = i / NGc;
                int xx  = pos % 66, rr = pos / 66;
                int gy = y + rr - 1, gx = xx - 1;
                uint4 v = {0u, 0u, 0u, 0u};
                if (gy >= 0 && gy < 64 && gx >= 0 && gx < 64)
                    v = *(const uint4*)&in[((size_t)((b * 64 + gy) * 64 + gx)) * CINF
                                           + ci0 + g * 8];
                *(uint4*)&s_in[kg][pos * CHUNK + ((g ^ (xx & SWM)) * 8)] = v;
            }
            __syncthreads();
        }
        if (step + 1 < NSTEPg) {
            const int nk = (step + 1) * 32;
            if (step & 1) {
#pragma unroll
                for (int t = 0; t < 9; ++t)
                    bbA[t] = *(const short8*)&wbase[t * tstride + nk];
            } else {
#pragma unroll
                for (int t = 0; t < 9; ++t)
                    bbB[t] = *(const short8*)&wbase[t * tstride + nk];
            }
        }
        const int gbase = kk >> 3;
#pragma unroll
        for (int t = 0; t < 9; ++t) {
            const int kh = t / 3, kw = t % 3;
            short8 a[4];
#pragma unroll
            for (int mf = 0; mf < 4; ++mf) {
                int xx = mf * 16 + l15 + kw;
                int g  = (gbase + lk) ^ (xx & SWM);
                a[mf] = *(const short8*)&s_in[kg][(kh * 66 + xx) * CHUNK + g * 8];
            }
            short8 cur = (step & 1) ? bbB[t] : bbA[t];
#pragma unroll
            for (int mf = 0; mf < 4; ++mf)
                acc[mf] = __builtin_amdgcn_mfma_f32_16x16x32_bf16(
                    cur, a[mf], acc[mf], 0, 0, 0);   // swapped: D[n][m]
        }
    }

    // ---- combine k-halves via LDS (16 KB, aliases staging buffers)
    __syncthreads();
    float* epi = (float*)&s_in[0][0];
    if (kg == 1) {
        float* dst = &epi[((wv * 64 + lane) * 4) * 4];
#pragma unroll
        for (int mf = 0; mf < 4; ++mf)
            *(f32x4*)&dst[mf * 4] = acc[mf];
    }
    __syncthreads();
    if (kg == 0) {
        const float* src = &epi[((wv * 64 + lane) * 4) * 4];
        int n = n_wave + lk * 4;
        float4 bv = *(const float4*)&bias[n];
#pragma unroll
        for (int mf = 0; mf < 4; ++mf) {
            f32x4 o = *(const f32x4*)&src[mf * 4];
            int x = mf * 16 + l15;
            float v0 = acc[mf][0] + o[0] + bv.x;
            float v1 = acc[mf][1] + o[1] + bv.y;
            float v2 = acc[mf][2] + o[2] + bv.z;
            float v3 = acc[mf][3] + o[3] + bv.w;
            if (do_relu) {
                v0 = fmaxf(v0, 0.f); v1 = fmaxf(v1, 0.f);
                v2 = fmaxf(v2, 0.f); v3 = fmaxf(v3, 0.f);
            }
            ushort4 pk;
            pk.x = f2bf(v0); pk.y = f2bf(v1); pk.z = f2bf(v2); pk.w = f2bf(v3);
            *(ushort4*)&out[((size_t)(b * HW + y * 64 + x)) * Cout + n] = pk;
        }
    }
}

// ---------------- per-PIXEL MLP (16 px/block, 1024 thr, K-split) -----------
// 2 k-groups x 8 waves; wave = 16M x 32N over its K-half (4 k-steps).
// Per-layer combine: group 1 dumps fp32 acc to scratch (two stride-16B
// halves -> 2-way-free), group 0 adds + bias + relu + pack to Cb.
__device__ __forceinline__ void mlp_ks(
    const short* __restrict__ A, short* __restrict__ Cb,
    float* __restrict__ scratch,
    const short* __restrict__ Wt, const float* __restrict__ bias,
    int kg, int wv, int lane, int l15, int lk, int xw)
{
    int n0 = wv * 32;
    f32x4 acc[2];
#pragma unroll
    for (int nf = 0; nf < 2; ++nf) acc[nf] = (f32x4){0.f, 0.f, 0.f, 0.f};

#pragma unroll
    for (int s = 0; s < 4; ++s) {
        int k0 = kg * 128 + s * 32;
        short8 bb[2];
#pragma unroll
        for (int nf = 0; nf < 2; ++nf)
            bb[nf] = *(const short8*)
                &Wt[(size_t)(n0 + nf * 16 + l15) * 256 + k0 + lk * 8];
        short8 a = *(const short8*)&A[(l15 * 256 + k0 + lk * 8) ^ xw];
#pragma unroll
        for (int nf = 0; nf < 2; ++nf)
            acc[nf] = __builtin_amdgcn_mfma_f32_16x16x32_bf16(
                bb[nf], a, acc[nf], 0, 0, 0);   // swapped: D[n][m=l15]
    }

    int slot = wv * 64 + lane;
    if (kg == 1) {
        *(f32x4*)&scratch[slot * 4]        = acc[0];
        *(f32x4*)&scratch[2048 + slot * 4] = acc[1];
    }
    __syncthreads();
    if (kg == 0) {
        f32x4 o0 = *(const f32x4*)&scratch[slot * 4];
        f32x4 o1 = *(const f32x4*)&scratch[2048 + slot * 4];
#pragma unroll
        for (int nf = 0; nf < 2; ++nf) {
            f32x4 o = nf ? o1 : o0;
            int n = n0 + nf * 16 + lk * 4;
            float4 bv = *(const float4*)&bias[n];
            float v0 = fmaxf(acc[nf][0] + o[0] + bv.x, 0.f);
            float v1 = fmaxf(acc[nf][1] + o[1] + bv.y, 0.f);
            float v2 = fmaxf(acc[nf][2] + o[2] + bv.z, 0.f);
            float v3 = fmaxf(acc[nf][3] + o[3] + bv.w, 0.f);
            ushort4 pk;
            pk.x = f2bf(v0); pk.y = f2bf(v1);
            pk.z = f2bf(v2); pk.w = f2bf(v3);
            *(ushort4*)&Cb[(l15 * 256 + n) ^ xw] = pk;
        }
    }
    __syncthreads();
}

__global__ __launch_bounds__(1024) void pixel_mlp_kernel(
    const short* __restrict__ h0pre,   // [NPX][256] bf16
    const float* __restrict__ cell,
    const float* __restrict__ w0,      // tail rows 2304,2305 (fp32)
    const short* __restrict__ wt1, const short* __restrict__ wt2,
    const short* __restrict__ wt3,
    const float* __restrict__ b1, const float* __restrict__ b2,
    const float* __restrict__ b3,
    const float* __restrict__ w4, const float* __restrict__ b4,
    float* __restrict__ rgb)           // [NPX][3] fp32
{
    __shared__ short bufs[2][16 * 256];   // 16 KB
    __shared__ float scratch[4096];       // 16 KB (tails / combine / sw4)

    int tid  = threadIdx.x;
    int kg   = tid >> 9;                  // 0/1
    int wv   = (tid >> 6) & 7;            // wave within group
    int lane = tid & 63;
    int l15  = lane & 15, lk = lane >> 4;

    float rc0 = cell[0] * 64.f;
    float rc1 = cell[1] * 64.f;

    float* tails = scratch;               // 512 floats
    if (tid < 128)
        ((float4*)tails)[tid] = ((const float4*)&w0[(size_t)2304 * 256])[tid];
    __syncthreads();

    // gather + cell term + relu -> bufs[0]; thread = (row=tid>>6, 4 ch)
    {
        int row = tid >> 6;               // 0..15
        int c   = (tid & 63) * 4;
        int p = blockIdx.x * 16 + row;
        const short* src = &h0pre[(size_t)p * 256];
        int xr = (row & 7) << 3;
        uint2 h4 = *(const uint2*)&src[c];
        float4 t0 = *(const float4*)&tails[c];
        float4 t1v = *(const float4*)&tails[256 + c];
        float v0 = fmaxf(bflo(h4.x) + rc0 * t0.x + rc1 * t1v.x, 0.f);
        float v1 = fmaxf(bfhi(h4.x) + rc0 * t0.y + rc1 * t1v.y, 0.f);
        float v2 = fmaxf(bflo(h4.y) + rc0 * t0.z + rc1 * t1v.z, 0.f);
        float v3 = fmaxf(bfhi(h4.y) + rc0 * t0.w + rc1 * t1v.w, 0.f);
        uint2 pk;
        pk.x = pack2(v0, v1); pk.y = pack2(v2, v3);
        *(uint2*)&bufs[0][(row * 256 + c) ^ xr] = pk;
    }
    __syncthreads();

    int xw = (l15 & 7) << 3;
    mlp_ks(bufs[0], bufs[1], scratch, wt1, b1, kg, wv, lane, l15, lk, xw);
    mlp_ks(bufs[1], bufs[0], scratch, wt2, b2, kg, wv, lane, l15, lk, xw);
    mlp_ks(bufs[0], bufs[1], scratch, wt3, b3, kg, wv, lane, l15, lk, xw);
    // final h in bufs[1]; scratch free

    float* sw4 = scratch;                 // 768 floats
    if (tid < 192) ((float4*)sw4)[tid] = ((const float4*)w4)[tid];
    __syncthreads();

    // final dot: one wave per row (16 waves), 4 ch/lane, full-wave shfl tree
    {
        int row = tid >> 6;               // 0..15
        int k   = lane * 4;
        const short* hrow = bufs[1];
        int xr = (row & 7) << 3;
        uint2 hv = *(const uint2*)&hrow[(row * 256 + k) ^ xr];
        const float* wp = &sw4[k * 3];
        float a0 = 0.f, a1 = 0.f, a2 = 0.f;
        float f;
        f = bflo(hv.x); a0 = fmaf(f, wp[0], a0); a1 = fmaf(f, wp[1],  a1); a2 = fmaf(f, wp[2],  a2);
        f = bfhi(hv.x); a0 = fmaf(f, wp[3], a0); a1 = fmaf(f, wp[4],  a1); a2 = fmaf(f, wp[5],  a2);
        f = bflo(hv.y); a0 = fmaf(f, wp[6], a0); a1 = fmaf(f, wp[7],  a1); a2 = fmaf(f, wp[8],  a2);
        f = bfhi(hv.y); a0 = fmaf(f, wp[9], a0); a1 = fmaf(f, wp[10], a1); a2 = fmaf(f, wp[11], a2);

#pragma unroll
        for (int m = 1; m < 64; m <<= 1) {
            a0 += __shfl_xor(a0, m);
            a1 += __shfl_xor(a1, m);
            a2 += __shfl_xor(a2, m);
        }
        if (lane == 0) {
            size_t p = (size_t)blockIdx.x * 16 + row;
            rgb[p * 3 + 0] = a0 + b4[0];
            rgb[p * 3 + 1] = a1 + b4[1];
            rgb[p * 3 + 2] = a2 + b4[2];
        }
    }
}

// ---------------- per-query 4-tap weighted gather --------------------------
__global__ __launch_bounds__(256) void query_kernel(
    const float* __restrict__ coord, const float* __restrict__ rgb,
    float* __restrict__ out)
{
    int q = blockIdx.x * 256 + threadIdx.x;
    if (q >= BQ) return;
    int b = q >> 13;

    float c0 = coord[(size_t)q * 2 + 0];
    float c1 = coord[(size_t)q * 2 + 1];
    const float rx = 1.f / 64.f;
    const float lo = -1.f + 1e-6f, hi = 1.f - 1e-6f, eps = 1e-6f;

    float area[4]; int pos[4];
#pragma unroll
    for (int ss = 0; ss < 4; ++ss) {
        float vx = (ss < 2) ? -1.f : 1.f;
        float vy = (ss & 1) ? 1.f : -1.f;
        float cy = fminf(fmaxf(c0 + vx * rx + eps, lo), hi);
        float cx = fminf(fmaxf(c1 + vy * rx + eps, lo), hi);
        int iy = (int)rintf(((cy + 1.f) * 64.f - 1.f) * 0.5f);
        int ix = (int)rintf(((cx + 1.f) * 64.f - 1.f) * 0.5f);
        iy = min(max(iy, 0), 63); ix = min(max(ix, 0), 63);
        float ly = -1.f + iy * (2.f / 63.f);
        float lx = -1.f + ix * (2.f / 63.f);
        float rel0 = (c0 - ly) * 64.f;
        float rel1 = (c1 - lx) * 64.f;
        area[ss] = fabsf(rel0 * rel1) + 1e-9f;
        pos[ss] = iy * 64 + ix;
    }
    float tot = area[0] + area[1] + area[2] + area[3];
    float r0 = 0.f, r1 = 0.f, r2 = 0.f;
#pragma unroll
    for (int ss = 0; ss < 4; ++ss) {
        float wt = area[3 - ss] / tot;
        const float* rp = &rgb[(size_t)((b << 12) + pos[ss]) * 3];
        r0 = fmaf(wt, rp[0], r0);
        r1 = fmaf(wt, rp[1], r1);
        r2 = fmaf(wt, rp[2], r2);
    }
    size_t o = (size_t)q * 3;
    out[o + 0] = r0; out[o + 1] = r1; out[o + 2] = r2;
}

// ---------------------------------------------------------------------------
extern "C" void kernel_launch(void* const* d_in, const int* in_sizes, int n_in,
                              void* d_out, int out_size, void* d_ws, size_t ws_size,
                              hipStream_t stream)
{
    const float* inp   = (const float*)d_in[0];
    const float* coord = (const float*)d_in[1];
    const float* cell  = (const float*)d_in[2];
    const float* c1w = (const float*)d_in[3];  const float* c1b = (const float*)d_in[4];
    const float* c2w = (const float*)d_in[5];  const float* c2b = (const float*)d_in[6];
    const float* c3w = (const float*)d_in[7];  const float* c3b = (const float*)d_in[8];
    const float* c4w = (const float*)d_in[9];  const float* c4b = (const float*)d_in[10];
    const float* w0  = (const float*)d_in[11]; const float* b0  = (const float*)d_in[12];
    const float* w1  = (const float*)d_in[13]; const float* b1  = (const float*)d_in[14];
    const float* w2  = (const float*)d_in[15]; const float* b2  = (const float*)d_in[16];
    const float* w3  = (const float*)d_in[17]; const float* b3  = (const float*)d_in[18];
    const float* w4  = (const float*)d_in[19]; const float* b4  = (const float*)d_in[20];
    float* out = (float*)d_out;

    char* p = (char*)d_ws;
    short* t1  = (short*)p; p += (size_t)4 << 20;        // c1/c3 out
    short* t2  = (short*)p; p += (size_t)4 << 20;        // c2/c4 out
    short* t3  = (short*)p; p += (size_t)4 << 20;        // h0pre
    short* wc2 = (short*)p; p += (size_t)9 * 128 * 64 * 2;
    short* wc3 = (short*)p; p += (size_t)9 * 256 * 128 * 2;
    short* wc4 = (short*)p; p += (size_t)9 * 256 * 256 * 2;
    short* wl0 = (short*)p; p += (size_t)9 * 256 * 256 * 2;
    short* wt1 = (short*)p; p += (size_t)256 * 256 * 2;
    short* wt2 = (short*)p; p += (size_t)256 * 256 * 2;
    short* wt3 = (short*)p; p += (size_t)256 * 256 * 2;
    float* rgb = (float*)p; p += (size_t)NPX * 3 * 4;

    // merged c1 + weight prep
    hipLaunchKernelGGL(prep_c1_kernel, dim3(256 + 6816), dim3(256), 0, stream,
                       inp, c1w, c1b, c2w, c3w, c4w, w0, w1, w2, w3,
                       t1, wc2, wc3, wc4, wl0, wt1, wt2, wt3);

    // encoder: all convs K-split 512-thread kernels
    hipLaunchKernelGGL((conv512_kernel<64, 32>), dim3(Bc * 2 * 64), dim3(512), 0, stream,
                       t1, wc2, c2b, t2, 128, 1);
    hipLaunchKernelGGL((conv512_kernel<128, 64>), dim3(Bc * 4 * 64), dim3(512), 0, stream,
                       t2, wc3, c3b, t1, 256, 1);
    hipLaunchKernelGGL((conv512_kernel<256, 64>), dim3(Bc * 4 * 64), dim3(512), 0, stream,
                       t1, wc4, c4b, t2, 256, 1);
    // layer0 as conv: +b0, NO relu -> h0pre
    hipLaunchKernelGGL((conv512_kernel<256, 64>), dim3(Bc * 4 * 64), dim3(512), 0, stream,
                       t2, wl0, b0, t3, 256, 0);

    // per-pixel MLP (8192 rows, K-split 1024 thr) then 4-tap query gather
    hipLaunchKernelGGL(pixel_mlp_kernel, dim3(NPX / 16), dim3(1024), 0, stream,
                       t3, cell, w0, wt1, wt2, wt3, b1, b2, b3, w4, b4, rgb);
    hipLaunchKernelGGL(query_kernel, dim3(BQ / 256), dim3(256), 0, stream,
                       coord, rgb, out);
}

// Round 20
// 113.122 us; speedup vs baseline: 1.2033x; 1.0001x over previous
//
#include <hip/hip_runtime.h>

// ---------------------------------------------------------------------------
// LIIF forward, bf16-MFMA, round 20 == round 18/16 verbatim (best measured,
// 113.1us, reproduced twice). Round 19's cooperative-launch encoder fusion
// failed correctness under the harness's graph capture (silent no-op /
// missing cross-phase ordering) — reverted.
//   - convs: 1 row x 64-Cout x K-split(2), 512 thr = 2 kg x 4 waves,
//     4Mfrag x 16N, CHUNK=64(32 for c2), 9-tap reg prefetch, XOR swizzle
//   - pixel_mlp: 1024 thr = 2 kg x 8 waves, fp32 LDS combine, shfl final
//   - merged prep+c1; per-query 4-tap gather
// ---------------------------------------------------------------------------

#define HW    4096
#define Bc    2
#define Qn    8192
#define BQ    16384   // Bc*Qn
#define NPX   8192    // Bc*HW

typedef __attribute__((ext_vector_type(8))) short short8;
typedef __attribute__((ext_vector_type(4))) float f32x4;

__device__ __forceinline__ unsigned short f2bf(float f) {
    unsigned int u = __builtin_bit_cast(unsigned int, f);
    u += 0x7FFFu + ((u >> 16) & 1u);            // RNE
    return (unsigned short)(u >> 16);
}
__device__ __forceinline__ float bflo(unsigned int u) {
    return __builtin_bit_cast(float, u << 16);
}
__device__ __forceinline__ float bfhi(unsigned int u) {
    return __builtin_bit_cast(float, u & 0xffff0000u);
}
__device__ __forceinline__ unsigned int pack2(float a, float b) {
    return (unsigned int)f2bf(a) | ((unsigned int)f2bf(b) << 16);
}

// ---------------- merged: c1 conv (blocks 0..255) + weight prep ------------
#define CO_T  16
#define ROWS  2

__global__ __launch_bounds__(256) void prep_c1_kernel(
    const float* __restrict__ in,  const float* __restrict__ c1w,
    const float* __restrict__ c1b,
    const float* __restrict__ c2w, const float* __restrict__ c3w,
    const float* __restrict__ c4w, const float* __restrict__ w0,
    const float* __restrict__ w1,  const float* __restrict__ w2,
    const float* __restrict__ w3,
    short* __restrict__ t1,
    short* __restrict__ wc2, short* __restrict__ wc3,
    short* __restrict__ wc4, short* __restrict__ wl0,
    short* __restrict__ wt1, short* __restrict__ wt2,
    short* __restrict__ wt3)
{
    __shared__ float sin_[3][ROWS + 2][66];
    __shared__ float sw_[CO_T][3][9];

    int tid = threadIdx.x;

    if (blockIdx.x < 256) {
        const int Cin = 3, Cout = 64;
        int bx = blockIdx.x;
        int rowb = bx & 31; bx >>= 5;
        int cob = bx & 3;
        int b   = bx >> 2;

        int x  = tid & 63;
        int wq = tid >> 6;
        int y0 = rowb * ROWS;

        float acc[4][ROWS];
#pragma unroll
        for (int k = 0; k < 4; ++k)
#pragma unroll
            for (int r = 0; r < ROWS; ++r) acc[k][r] = 0.f;

        int tot_in = 3 * (ROWS + 2) * 66;
        for (int idx = tid; idx < tot_in; idx += 256) {
            int xx = idx % 66;
            int t2 = idx / 66;
            int rr = t2 % (ROWS + 2);
            int c  = t2 / (ROWS + 2);
            int gy = y0 - 1 + rr;
            int gx = xx - 1;
            float v = 0.f;
            if (gy >= 0 && gy < 64 && gx >= 0 && gx < 64)
                v = in[((size_t)b * Cin + c) * HW + gy * 64 + gx];
            sin_[c][rr][xx] = v;
        }
        int tot_w = CO_T * 3 * 9;
        for (int idx = tid; idx < tot_w; idx += 256) {
            int t  = idx % 9;
            int t2 = idx / 9;
            int c  = t2 % 3;
            int col = t2 / 3;
            sw_[col][c][t] = c1w[((size_t)(cob * CO_T + col) * Cin + c) * 9 + t];
        }
        __syncthreads();

#pragma unroll
        for (int c = 0; c < 3; ++c) {
            float iv[ROWS + 2][3];
#pragma unroll
            for (int rr = 0; rr < ROWS + 2; ++rr)
#pragma unroll
                for (int d = 0; d < 3; ++d)
                    iv[rr][d] = sin_[c][rr][x + d];
#pragma unroll
            for (int k = 0; k < 4; ++k) {
                float wv[9];
#pragma unroll
                for (int t = 0; t < 9; ++t) wv[t] = sw_[wq * 4 + k][c][t];
#pragma unroll
                for (int kh = 0; kh < 3; ++kh)
#pragma unroll
                    for (int kw = 0; kw < 3; ++kw) {
                        float wvv = wv[kh * 3 + kw];
#pragma unroll
                        for (int r = 0; r < ROWS; ++r)
                            acc[k][r] = fmaf(iv[r + kh][kw], wvv, acc[k][r]);
                    }
            }
        }

#pragma unroll
        for (int k = 0; k < 4; ++k) {
            int co = cob * CO_T + wq * 4 + k;
            float bv = c1b[co];
#pragma unroll
            for (int r = 0; r < ROWS; ++r) {
                float v = fmaxf(acc[k][r] + bv, 0.f);
                int pos = (y0 + r) * 64 + x;
                t1[((size_t)b * HW + pos) * Cout + co] = (short)f2bf(v);
            }
        }
        return;
    }

    const int S1 = 9 * 128 * 64;
    const int S2 = 9 * 256 * 128;
    const int S3 = 9 * 256 * 256;
    int i = (blockIdx.x - 256) * 256 + tid;
    if (i < S1) {
        int ci = i & 63, co = (i >> 6) & 127, t = i >> 13;
        wc2[i] = (short)f2bf(c2w[((size_t)co * 64 + ci) * 9 + t]);
        return;
    }
    i -= S1;
    if (i < S2) {
        int ci = i & 127, co = (i >> 7) & 255, t = i >> 15;
        wc3[i] = (short)f2bf(c3w[((size_t)co * 128 + ci) * 9 + t]);
        return;
    }
    i -= S2;
    if (i < S3) {
        int ci = i & 255, co = (i >> 8) & 255, t = i >> 16;
        wc4[i] = (short)f2bf(c4w[((size_t)co * 256 + ci) * 9 + t]);
        return;
    }
    i -= S3;
    if (i < S3) {
        int ci = i & 255, co = (i >> 8) & 255, t = i >> 16;
        wl0[i] = (short)f2bf(w0[((size_t)ci * 9 + t) * 256 + co]);
        return;
    }
    i -= S3;
    if (i < 65536) { wt1[i] = (short)f2bf(w1[(size_t)(i & 255) * 256 + (i >> 8)]); return; }
    i -= 65536;
    if (i < 65536) { wt2[i] = (short)f2bf(w2[(size_t)(i & 255) * 256 + (i >> 8)]); return; }
    i -= 65536;
    if (i < 65536) { wt3[i] = (short)f2bf(w3[(size_t)(i & 255) * 256 + (i >> 8)]); }
}

// ---------------- K-split conv: 512 thr = 2 k-groups x 4 waves -------------
// Group g computes the same 64x64 tile over K-half g, own LDS buffer.
// Group 1 -> LDS fp32, group 0 combines + bias/relu/store.
template<int CINF, int CHUNK>
__global__ __launch_bounds__(512) void conv512_kernel(
    const short* __restrict__ in, const short* __restrict__ wt9,
    const float* __restrict__ bias, short* __restrict__ out,
    int Cout, int do_relu)
{
    constexpr int KHALF  = CINF / 2;
    constexpr int NGc    = CHUNK / 8;
    constexpr int SWM    = NGc - 1;            // swizzle mask
    constexpr int NSTEPg = KHALF / 32;
    __shared__ short s_in[2][3 * 66 * CHUNK];

    int bx  = blockIdx.x;
    int y   = bx & 63; bx >>= 6;
    int nco = Cout >> 6;
    int cob = bx % nco;
    int b   = bx / nco;

    int tid  = threadIdx.x;
    int kg   = tid >> 8;                       // k-group 0/1
    int ltid = tid & 255;
    int wv   = (tid >> 6) & 3;
    int lane = tid & 63;
    int l15  = lane & 15, lk = lane >> 4;
    int n_wave = cob * 64 + wv * 16;
    int koff = kg * KHALF;

    const short* wbase = &wt9[((size_t)(n_wave + l15)) * CINF + koff + lk * 8];
    const size_t tstride = (size_t)Cout * CINF;

    f32x4 acc[4];
#pragma unroll
    for (int mf = 0; mf < 4; ++mf) acc[mf] = (f32x4){0.f, 0.f, 0.f, 0.f};

    short8 bbA[9], bbB[9];
#pragma unroll
    for (int t = 0; t < 9; ++t)
        bbA[t] = *(const short8*)&wbase[t * tstride];

#pragma unroll
    for (int step = 0; step < NSTEPg; ++step) {
        const int kabs = step * 32;
        const int chnk = kabs / CHUNK;
        const int kk   = kabs % CHUNK;
        if (kk == 0) {
            if (step) __syncthreads();
            const int ci0 = koff + chnk * CHUNK;
            for (int i = ltid; i < 3 * 66 * NGc; i += 256) {
                int g   = i % NGc;
                int pos = i / NGc;
                int xx  = pos % 66, rr = pos / 66;
                int gy = y + rr - 1, gx = xx - 1;
                uint4 v = {0u, 0u, 0u, 0u};
                if (gy >= 0 && gy < 64 && gx >= 0 && gx < 64)
                    v = *(const uint4*)&in[((size_t)((b * 64 + gy) * 64 + gx)) * CINF
                                           + ci0 + g * 8];
                *(uint4*)&s_in[kg][pos * CHUNK + ((g ^ (xx & SWM)) * 8)] = v;
            }
            __syncthreads();
        }
        if (step + 1 < NSTEPg) {
            const int nk = (step + 1) * 32;
            if (step & 1) {
#pragma unroll
                for (int t = 0; t < 9; ++t)
                    bbA[t] = *(const short8*)&wbase[t * tstride + nk];
            } else {
#pragma unroll
                for (int t = 0; t < 9; ++t)
                    bbB[t] = *(const short8*)&wbase[t * tstride + nk];
            }
        }
        const int gbase = kk >> 3;
#pragma unroll
        for (int t = 0; t < 9; ++t) {
            const int kh = t / 3, kw = t % 3;
            short8 a[4];
#pragma unroll
            for (int mf = 0; mf < 4; ++mf) {
                int xx = mf * 16 + l15 + kw;
                int g  = (gbase + lk) ^ (xx & SWM);
                a[mf] = *(const short8*)&s_in[kg][(kh * 66 + xx) * CHUNK + g * 8];
            }
            short8 cur = (step & 1) ? bbB[t] : bbA[t];
#pragma unroll
            for (int mf = 0; mf < 4; ++mf)
                acc[mf] = __builtin_amdgcn_mfma_f32_16x16x32_bf16(
                    cur, a[mf], acc[mf], 0, 0, 0);   // swapped: D[n][m]
        }
    }

    // ---- combine k-halves via LDS (16 KB, aliases staging buffers)
    __syncthreads();
    float* epi = (float*)&s_in[0][0];
    if (kg == 1) {
        float* dst = &epi[((wv * 64 + lane) * 4) * 4];
#pragma unroll
        for (int mf = 0; mf < 4; ++mf)
            *(f32x4*)&dst[mf * 4] = acc[mf];
    }
    __syncthreads();
    if (kg == 0) {
        const float* src = &epi[((wv * 64 + lane) * 4) * 4];
        int n = n_wave + lk * 4;
        float4 bv = *(const float4*)&bias[n];
#pragma unroll
        for (int mf = 0; mf < 4; ++mf) {
            f32x4 o = *(const f32x4*)&src[mf * 4];
            int x = mf * 16 + l15;
            float v0 = acc[mf][0] + o[0] + bv.x;
            float v1 = acc[mf][1] + o[1] + bv.y;
            float v2 = acc[mf][2] + o[2] + bv.z;
            float v3 = acc[mf][3] + o[3] + bv.w;
            if (do_relu) {
                v0 = fmaxf(v0, 0.f); v1 = fmaxf(v1, 0.f);
                v2 = fmaxf(v2, 0.f); v3 = fmaxf(v3, 0.f);
            }
            ushort4 pk;
            pk.x = f2bf(v0); pk.y = f2bf(v1); pk.z = f2bf(v2); pk.w = f2bf(v3);
            *(ushort4*)&out[((size_t)(b * HW + y * 64 + x)) * Cout + n] = pk;
        }
    }
}

// ---------------- per-PIXEL MLP (16 px/block, 1024 thr, K-split) -----------
// 2 k-groups x 8 waves; wave = 16M x 32N over its K-half (4 k-steps).
// Per-layer combine: group 1 dumps fp32 acc to scratch (two stride-16B
// halves -> 2-way-free), group 0 adds + bias + relu + pack to Cb.
__device__ __forceinline__ void mlp_ks(
    const short* __restrict__ A, short* __restrict__ Cb,
    float* __restrict__ scratch,
    const short* __restrict__ Wt, const float* __restrict__ bias,
    int kg, int wv, int lane, int l15, int lk, int xw)
{
    int n0 = wv * 32;
    f32x4 acc[2];
#pragma unroll
    for (int nf = 0; nf < 2; ++nf) acc[nf] = (f32x4){0.f, 0.f, 0.f, 0.f};

#pragma unroll
    for (int s = 0; s < 4; ++s) {
        int k0 = kg * 128 + s * 32;
        short8 bb[2];
#pragma unroll
        for (int nf = 0; nf < 2; ++nf)
            bb[nf] = *(const short8*)
                &Wt[(size_t)(n0 + nf * 16 + l15) * 256 + k0 + lk * 8];
        short8 a = *(const short8*)&A[(l15 * 256 + k0 + lk * 8) ^ xw];
#pragma unroll
        for (int nf = 0; nf < 2; ++nf)
            acc[nf] = __builtin_amdgcn_mfma_f32_16x16x32_bf16(
                bb[nf], a, acc[nf], 0, 0, 0);   // swapped: D[n][m=l15]
    }

    int slot = wv * 64 + lane;
    if (kg == 1) {
        *(f32x4*)&scratch[slot * 4]        = acc[0];
        *(f32x4*)&scratch[2048 + slot * 4] = acc[1];
    }
    __syncthreads();
    if (kg == 0) {
        f32x4 o0 = *(const f32x4*)&scratch[slot * 4];
        f32x4 o1 = *(const f32x4*)&scratch[2048 + slot * 4];
#pragma unroll
        for (int nf = 0; nf < 2; ++nf) {
            f32x4 o = nf ? o1 : o0;
            int n = n0 + nf * 16 + lk * 4;
            float4 bv = *(const float4*)&bias[n];
            float v0 = fmaxf(acc[nf][0] + o[0] + bv.x, 0.f);
            float v1 = fmaxf(acc[nf][1] + o[1] + bv.y, 0.f);
            float v2 = fmaxf(acc[nf][2] + o[2] + bv.z, 0.f);
            float v3 = fmaxf(acc[nf][3] + o[3] + bv.w, 0.f);
            ushort4 pk;
            pk.x = f2bf(v0); pk.y = f2bf(v1);
            pk.z = f2bf(v2); pk.w = f2bf(v3);
            *(ushort4*)&Cb[(l15 * 256 + n) ^ xw] = pk;
        }
    }
    __syncthreads();
}

__global__ __launch_bounds__(1024) void pixel_mlp_kernel(
    const short* __restrict__ h0pre,   // [NPX][256] bf16
    const float* __restrict__ cell,
    const float* __restrict__ w0,      // tail rows 2304,2305 (fp32)
    const short* __restrict__ wt1, const short* __restrict__ wt2,
    const short* __restrict__ wt3,
    const float* __restrict__ b1, const float* __restrict__ b2,
    const float* __restrict__ b3,
    const float* __restrict__ w4, const float* __restrict__ b4,
    float* __restrict__ rgb)           // [NPX][3] fp32
{
    __shared__ short bufs[2][16 * 256];   // 16 KB
    __shared__ float scratch[4096];       // 16 KB (tails / combine / sw4)

    int tid  = threadIdx.x;
    int kg   = tid >> 9;                  // 0/1
    int wv   = (tid >> 6) & 7;            // wave within group
    int lane = tid & 63;
    int l15  = lane & 15, lk = lane >> 4;

    float rc0 = cell[0] * 64.f;
    float rc1 = cell[1] * 64.f;

    float* tails = scratch;               // 512 floats
    if (tid < 128)
        ((float4*)tails)[tid] = ((const float4*)&w0[(size_t)2304 * 256])[tid];
    __syncthreads();

    // gather + cell term + relu -> bufs[0]; thread = (row=tid>>6, 4 ch)
    {
        int row = tid >> 6;               // 0..15
        int c   = (tid & 63) * 4;
        int p = blockIdx.x * 16 + row;
        const short* src = &h0pre[(size_t)p * 256];
        int xr = (row & 7) << 3;
        uint2 h4 = *(const uint2*)&src[c];
        float4 t0 = *(const float4*)&tails[c];
        float4 t1v = *(const float4*)&tails[256 + c];
        float v0 = fmaxf(bflo(h4.x) + rc0 * t0.x + rc1 * t1v.x, 0.f);
        float v1 = fmaxf(bfhi(h4.x) + rc0 * t0.y + rc1 * t1v.y, 0.f);
        float v2 = fmaxf(bflo(h4.y) + rc0 * t0.z + rc1 * t1v.z, 0.f);
        float v3 = fmaxf(bfhi(h4.y) + rc0 * t0.w + rc1 * t1v.w, 0.f);
        uint2 pk;
        pk.x = pack2(v0, v1); pk.y = pack2(v2, v3);
        *(uint2*)&bufs[0][(row * 256 + c) ^ xr] = pk;
    }
    __syncthreads();

    int xw = (l15 & 7) << 3;
    mlp_ks(bufs[0], bufs[1], scratch, wt1, b1, kg, wv, lane, l15, lk, xw);
    mlp_ks(bufs[1], bufs[0], scratch, wt2, b2, kg, wv, lane, l15, lk, xw);
    mlp_ks(bufs[0], bufs[1], scratch, wt3, b3, kg, wv, lane, l15, lk, xw);
    // final h in bufs[1]; scratch free

    float* sw4 = scratch;                 // 768 floats
    if (tid < 192) ((float4*)sw4)[tid] = ((const float4*)w4)[tid];
    __syncthreads();

    // final dot: one wave per row (16 waves), 4 ch/lane, full-wave shfl tree
    {
        int row = tid >> 6;               // 0..15
        int k   = lane * 4;
        const short* hrow = bufs[1];
        int xr = (row & 7) << 3;
        uint2 hv = *(const uint2*)&hrow[(row * 256 + k) ^ xr];
        const float* wp = &sw4[k * 3];
        float a0 = 0.f, a1 = 0.f, a2 = 0.f;
        float f;
        f = bflo(hv.x); a0 = fmaf(f, wp[0], a0); a1 = fmaf(f, wp[1],  a1); a2 = fmaf(f, wp[2],  a2);
        f = bfhi(hv.x); a0 = fmaf(f, wp[3], a0); a1 = fmaf(f, wp[4],  a1); a2 = fmaf(f, wp[5],  a2);
        f = bflo(hv.y); a0 = fmaf(f, wp[6], a0); a1 = fmaf(f, wp[7],  a1); a2 = fmaf(f, wp[8],  a2);
        f = bfhi(hv.y); a0 = fmaf(f, wp[9], a0); a1 = fmaf(f, wp[10], a1); a2 = fmaf(f, wp[11], a2);

#pragma unroll
        for (int m = 1; m < 64; m <<= 1) {
            a0 += __shfl_xor(a0, m);
            a1 += __shfl_xor(a1, m);
            a2 += __shfl_xor(a2, m);
        }
        if (lane == 0) {
            size_t p = (size_t)blockIdx.x * 16 + row;
            rgb[p * 3 + 0] = a0 + b4[0];
            rgb[p * 3 + 1] = a1 + b4[1];
            rgb[p * 3 + 2] = a2 + b4[2];
        }
    }
}

// ---------------- per-query 4-tap weighted gather --------------------------
__global__ __launch_bounds__(256) void query_kernel(
    const float* __restrict__ coord, const float* __restrict__ rgb,
    float* __restrict__ out)
{
    int q = blockIdx.x * 256 + threadIdx.x;
    if (q >= BQ) return;
    int b = q >> 13;

    float c0 = coord[(size_t)q * 2 + 0];
    float c1 = coord[(size_t)q * 2 + 1];
    const float rx = 1.f / 64.f;
    const float lo = -1.f + 1e-6f, hi = 1.f - 1e-6f, eps = 1e-6f;

    float area[4]; int pos[4];
#pragma unroll
    for (int ss = 0; ss < 4; ++ss) {
        float vx = (ss < 2) ? -1.f : 1.f;
        float vy = (ss & 1) ? 1.f : -1.f;
        float cy = fminf(fmaxf(c0 + vx * rx + eps, lo), hi);
        float cx = fminf(fmaxf(c1 + vy * rx + eps, lo), hi);
        int iy = (int)rintf(((cy + 1.f) * 64.f - 1.f) * 0.5f);
        int ix = (int)rintf(((cx + 1.f) * 64.f - 1.f) * 0.5f);
        iy = min(max(iy, 0), 63); ix = min(max(ix, 0), 63);
        float ly = -1.f + iy * (2.f / 63.f);
        float lx = -1.f + ix * (2.f / 63.f);
        float rel0 = (c0 - ly) * 64.f;
        float rel1 = (c1 - lx) * 64.f;
        area[ss] = fabsf(rel0 * rel1) + 1e-9f;
        pos[ss] = iy * 64 + ix;
    }
    float tot = area[0] + area[1] + area[2] + area[3];
    float r0 = 0.f, r1 = 0.f, r2 = 0.f;
#pragma unroll
    for (int ss = 0; ss < 4; ++ss) {
        float wt = area[3 - ss] / tot;
        const float* rp = &rgb[(size_t)((b << 12) + pos[ss]) * 3];
        r0 = fmaf(wt, rp[0], r0);
        r1 = fmaf(wt, rp[1], r1);
        r2 = fmaf(wt, rp[2], r2);
    }
    size_t o = (size_t)q * 3;
    out[o + 0] = r0; out[o + 1] = r1; out[o + 2] = r2;
}

// ---------------------------------------------------------------------------
extern "C" void kernel_launch(void* const* d_in, const int* in_sizes, int n_in,
                              void* d_out, int out_size, void* d_ws, size_t ws_size,
                              hipStream_t stream)
{
    const float* inp   = (const float*)d_in[0];
    const float* coord = (const float*)d_in[1];
    const float* cell  = (const float*)d_in[2];
    const float* c1w = (const float*)d_in[3];  const float* c1b = (const float*)d_in[4];
    const float* c2w = (const float*)d_in[5];  const float* c2b = (const float*)d_in[6];
    const float* c3w = (const float*)d_in[7];  const float* c3b = (const float*)d_in[8];
    const float* c4w = (const float*)d_in[9];  const float* c4b = (const float*)d_in[10];
    const float* w0  = (const float*)d_in[11]; const float* b0  = (const float*)d_in[12];
    const float* w1  = (const float*)d_in[13]; const float* b1  = (const float*)d_in[14];
    const float* w2  = (const float*)d_in[15]; const float* b2  = (const float*)d_in[16];
    const float* w3  = (const float*)d_in[17]; const float* b3  = (const float*)d_in[18];
    const float* w4  = (const float*)d_in[19]; const float* b4  = (const float*)d_in[20];
    float* out = (float*)d_out;

    char* p = (char*)d_ws;
    short* t1  = (short*)p; p += (size_t)4 << 20;        // c1/c3 out
    short* t2  = (short*)p; p += (size_t)4 << 20;        // c2/c4 out
    short* t3  = (short*)p; p += (size_t)4 << 20;        // h0pre
    short* wc2 = (short*)p; p += (size_t)9 * 128 * 64 * 2;
    short* wc3 = (short*)p; p += (size_t)9 * 256 * 128 * 2;
    short* wc4 = (short*)p; p += (size_t)9 * 256 * 256 * 2;
    short* wl0 = (short*)p; p += (size_t)9 * 256 * 256 * 2;
    short* wt1 = (short*)p; p += (size_t)256 * 256 * 2;
    short* wt2 = (short*)p; p += (size_t)256 * 256 * 2;
    short* wt3 = (short*)p; p += (size_t)256 * 256 * 2;
    float* rgb = (float*)p; p += (size_t)NPX * 3 * 4;

    // merged c1 + weight prep
    hipLaunchKernelGGL(prep_c1_kernel, dim3(256 + 6816), dim3(256), 0, stream,
                       inp, c1w, c1b, c2w, c3w, c4w, w0, w1, w2, w3,
                       t1, wc2, wc3, wc4, wl0, wt1, wt2, wt3);

    // encoder: all convs K-split 512-thread kernels
    hipLaunchKernelGGL((conv512_kernel<64, 32>), dim3(Bc * 2 * 64), dim3(512), 0, stream,
                       t1, wc2, c2b, t2, 128, 1);
    hipLaunchKernelGGL((conv512_kernel<128, 64>), dim3(Bc * 4 * 64), dim3(512), 0, stream,
                       t2, wc3, c3b, t1, 256, 1);
    hipLaunchKernelGGL((conv512_kernel<256, 64>), dim3(Bc * 4 * 64), dim3(512), 0, stream,
                       t1, wc4, c4b, t2, 256, 1);
    // layer0 as conv: +b0, NO relu -> h0pre
    hipLaunchKernelGGL((conv512_kernel<256, 64>), dim3(Bc * 4 * 64), dim3(512), 0, stream,
                       t2, wl0, b0, t3, 256, 0);

    // per-pixel MLP (8192 rows, K-split 1024 thr) then 4-tap query gather
    hipLaunchKernelGGL(pixel_mlp_kernel, dim3(NPX / 16), dim3(1024), 0, stream,
                       t3, cell, w0, wt1, wt2, wt3, b1, b2, b3, w4, b4, rgb);
    hipLaunchKernelGGL(query_kernel, dim3(BQ / 256), dim3(256), 0, stream,
                       coord, rgb, out);
}